// Round 1
// 982.113 us; speedup vs baseline: 1.0990x; 1.0990x over previous
//
#include <hip/hip_runtime.h>

#define NPTS   16384   // B*H*W
#define KCB    8192    // codebook entries
#define CDIM   256
#define HWSZ   1024    // 32*32
#define NB     16      // batch

typedef __bf16 bf16;
typedef __bf16 bf16x4v __attribute__((ext_vector_type(4)));
typedef __bf16 bf16x8v __attribute__((ext_vector_type(8)));
typedef float  f32x4v  __attribute__((ext_vector_type(4)));
typedef float  f32x2v  __attribute__((ext_vector_type(2)));

// flat float offsets in d_out (return order: quantized, loss, perplexity, indices, soft_codes)
#define OUT1 4194304
#define OUT2 4194305
#define OUT3 4194306
#define OUT4 4210690

#define MAX_RESCUE 4096
#define ENT_INTS   16      // [n, cnt, k0..k13]

// ---------------- async 16B global -> LDS ----------------
typedef __attribute__((address_space(1))) unsigned int as1_u32;
typedef __attribute__((address_space(3))) unsigned int as3_u32;
__device__ __forceinline__ void glds16(const bf16* g, bf16* l) {
  __builtin_amdgcn_global_load_lds((as1_u32*)(g), (as3_u32*)(l), 16, 0, 0);
}

// ---------------- K1: normalize codebook rows, split hi/lo bf16 ----------------
__global__ void k_norm_emb(const float* __restrict__ emb,
                           bf16* __restrict__ wn_hi, bf16* __restrict__ wn_lo) {
  const int lane = threadIdx.x & 63;
  const int row  = (blockIdx.x << 2) + (threadIdx.x >> 6);   // one wave per row
  const float4 v = *(const float4*)(emb + (size_t)row * CDIM + (lane << 2));
  float ss = v.x*v.x + v.y*v.y + v.z*v.z + v.w*v.w;
#pragma unroll
  for (int off = 1; off < 64; off <<= 1) ss += __shfl_xor(ss, off, 64);
  const float inv = 1.0f / fmaxf(sqrtf(ss), 1e-12f);
  const float a0 = v.x*inv, a1 = v.y*inv, a2 = v.z*inv, a3 = v.w*inv;
  const bf16 h0 = (bf16)a0, h1 = (bf16)a1, h2 = (bf16)a2, h3 = (bf16)a3;
  const bf16 l0 = (bf16)(a0 - (float)h0), l1 = (bf16)(a1 - (float)h1),
             l2 = (bf16)(a2 - (float)h2), l3 = (bf16)(a3 - (float)h3);
  *(bf16x4v*)(wn_hi + (size_t)row * CDIM + (lane << 2)) = (bf16x4v){h0, h1, h2, h3};
  *(bf16x4v*)(wn_lo + (size_t)row * CDIM + (lane << 2)) = (bf16x4v){l0, l1, l2, l3};
}

// ---------------- K2: transpose [B,C,H,W]->[N,C], L2-normalize, split hi/lo ----------------
__global__ void k_norm_x(const float* __restrict__ in,
                         bf16* __restrict__ fn_hi, bf16* __restrict__ fn_lo) {
  __shared__ float xs[32][257];
  __shared__ float inv_s[32];
  const int t = threadIdx.x;
  const int b = blockIdx.y;            // 16
  const int hw0 = blockIdx.x << 5;     // 32 hw rows per block
  const int hwo = t & 31, cb = t >> 5; // cb in [0,8)
  const float* src = in + (size_t)b * CDIM * HWSZ + hw0 + hwo;
#pragma unroll
  for (int it = 0; it < 32; ++it) {
    const int c = cb + (it << 3);
    xs[hwo][c] = src[(size_t)c * HWSZ];   // coalesced along hw
  }
  __syncthreads();
  const int wv = t >> 6, lane = t & 63;
#pragma unroll
  for (int j = 0; j < 8; ++j) {
    const int r = wv + (j << 2);
    float ss = 0.f;
#pragma unroll
    for (int e = 0; e < 4; ++e) { const float x = xs[r][lane + (e << 6)]; ss = fmaf(x, x, ss); }
#pragma unroll
    for (int off = 1; off < 64; off <<= 1) ss += __shfl_xor(ss, off, 64);
    if (lane == 0) inv_s[r] = 1.0f / fmaxf(sqrtf(ss), 1e-12f);
  }
  __syncthreads();
#pragma unroll 4
  for (int r = 0; r < 32; ++r) {
    const float v = xs[r][t] * inv_s[r];
    const bf16 h = (bf16)v;
    const bf16 l = (bf16)(v - (float)h);
    const size_t n = (size_t)b * HWSZ + hw0 + r;
    fn_hi[n * CDIM + t] = h;   // coalesced along c
    fn_lo[n * CDIM + t] = l;
  }
}

// ---------------- K3: split-bf16 MFMA GEMM -> unnormalized exp(-distance) ----------------
// Grid: 8192 1-D blocks. XCD-aware supertile swizzle:
//  bid = g*8 + xcd (HW round-robin); XCD x owns row-tiles [16x,16x+16) and walks
//  8 supertiles of 16 row-tiles x 8 col-tiles. Per-supertile working set:
//  A 16*128KB=2MB (resident for whole XCD pass) + B 8*128KB=1MB -> fits 4MB L2.
__global__ __launch_bounds__(256) void k_gemm(
    const bf16* __restrict__ fn_hi, const bf16* __restrict__ fn_lo,
    const bf16* __restrict__ wn_hi, const bf16* __restrict__ wn_lo,
    float* __restrict__ soft) {
  __shared__ __align__(16) bf16 Ah[128 * 32];
  __shared__ __align__(16) bf16 Al[128 * 32];
  __shared__ __align__(16) bf16 Bh[128 * 32];
  __shared__ __align__(16) bf16 Bl[128 * 32];
  const int t = threadIdx.x;

  const int bid = blockIdx.x;
  const int xcd = bid & 7;
  const int g   = bid >> 3;             // 0..1023 per XCD
  const int s   = (xcd << 3) + (g >> 7);  // supertile 0..63 ; s>>3 == xcd
  const int w   = g & 127;
  const int rowt = ((s >> 3) << 4) + (w >> 3);   // 0..127
  const int colt = ((s & 7) << 3) + (w & 7);     // 0..63
  const int row0 = rowt << 7;   // data points
  const int col0 = colt << 7;   // codebook

  const int r0 = t >> 2;
  const int cs = (t & 3) << 3;
  const int wv = t >> 6, lane = t & 63;
  const int wm = (wv & 1) << 6, wnn = (wv >> 1) << 6;
  const int ml = lane & 15, quad = lane >> 4;

  const size_t gA0 = (size_t)(row0 + r0) * CDIM + cs;
  const size_t gA1 = gA0 + (size_t)64 * CDIM;
  const size_t gB0 = (size_t)(col0 + r0) * CDIM + cs;
  const size_t gB1 = gB0 + (size_t)64 * CDIM;

  f32x4v acc[4][4] = {};

  for (int c0 = 0; c0 < CDIM; c0 += 32) {
    __syncthreads();
    glds16(fn_hi + gA0 + c0, Ah + t * 8);
    glds16(fn_hi + gA1 + c0, Ah + (t + 256) * 8);
    glds16(fn_lo + gA0 + c0, Al + t * 8);
    glds16(fn_lo + gA1 + c0, Al + (t + 256) * 8);
    glds16(wn_hi + gB0 + c0, Bh + t * 8);
    glds16(wn_hi + gB1 + c0, Bh + (t + 256) * 8);
    glds16(wn_lo + gB0 + c0, Bl + t * 8);
    glds16(wn_lo + gB1 + c0, Bl + (t + 256) * 8);
    __syncthreads();
    bf16x8v ah[4], alo[4], bh[4], blo[4];
#pragma unroll
    for (int i = 0; i < 4; ++i) {
      const int ra = (wm + 16 * i + ml) * 32 + quad * 8;
      const int rb = (wnn + 16 * i + ml) * 32 + quad * 8;
      ah[i]  = *(const bf16x8v*)(Ah + ra);
      alo[i] = *(const bf16x8v*)(Al + ra);
      bh[i]  = *(const bf16x8v*)(Bh + rb);
      blo[i] = *(const bf16x8v*)(Bl + rb);
    }
#pragma unroll
    for (int i = 0; i < 4; ++i)
#pragma unroll
      for (int j = 0; j < 4; ++j) {
        acc[i][j] = __builtin_amdgcn_mfma_f32_16x16x32_bf16(alo[i], bh[j], acc[i][j], 0, 0, 0);
        acc[i][j] = __builtin_amdgcn_mfma_f32_16x16x32_bf16(ah[i], blo[j], acc[i][j], 0, 0, 0);
        acc[i][j] = __builtin_amdgcn_mfma_f32_16x16x32_bf16(ah[i], bh[j], acc[i][j], 0, 0, 0);
      }
  }
  // epilogue: p_un = exp(2*dot - 2) ; C/D layout: col=lane&15, row=quad*4+reg
  // nontemporal: 536MB stream must not evict the L2-resident A/B panels
#pragma unroll
  for (int i = 0; i < 4; ++i) {
#pragma unroll
    for (int r = 0; r < 4; ++r) {
      const size_t nrow = (size_t)row0 + wm + 16 * i + quad * 4 + r;
      float* dst = soft + nrow * KCB + col0 + wnn + ml;
#pragma unroll
      for (int j = 0; j < 4; ++j)
        __builtin_nontemporal_store(__expf(fmaf(2.0f, acc[i][j][r], -2.0f)), dst + 16 * j);
    }
  }
}

// ---------------- K4: per-row softmax normalize (in place) + approx argmax + near-tie rescue ----------------
__global__ __launch_bounds__(256) void k_softnorm(float* __restrict__ soft,
                                                  int* __restrict__ ws_idx,
                                                  int* __restrict__ rescue,
                                                  int* __restrict__ rescue_cnt) {
  const int t = threadIdx.x;
  const size_t n = blockIdx.x;
  float* row = soft + n * (size_t)KCB;
  f32x2v v[16];
  float sum = 0.f, bp = -1.f;
  int bk = 0;
#pragma unroll
  for (int i = 0; i < 16; ++i) {
    v[i] = __builtin_nontemporal_load((const f32x2v*)(row + i * 512 + t * 2));
    const int k0 = i * 512 + t * 2;
    if (v[i][0] > bp) { bp = v[i][0]; bk = k0; }
    if (v[i][1] > bp) { bp = v[i][1]; bk = k0 + 1; }
    sum += v[i][0] + v[i][1];
  }
#pragma unroll
  for (int off = 1; off < 64; off <<= 1) {
    sum += __shfl_xor(sum, off, 64);
    const float op = __shfl_xor(bp, off, 64);
    const int   ok = __shfl_xor(bk, off, 64);
    if (op > bp || (op == bp && ok < bk)) { bp = op; bk = ok; }
  }
  __shared__ float s_sum[4], s_bp[4];
  __shared__ int s_bk[4];
  __shared__ int s_cand[16];
  __shared__ int s_ccnt;
  const int wv = t >> 6;
  if (t == 0) s_ccnt = 0;
  if ((t & 63) == 0) { s_sum[wv] = sum; s_bp[wv] = bp; s_bk[wv] = bk; }
  __syncthreads();
  sum = s_sum[0] + s_sum[1] + s_sum[2] + s_sum[3];
  bp = s_bp[0]; bk = s_bk[0];
#pragma unroll
  for (int w2 = 1; w2 < 4; ++w2) {
    const float op = s_bp[w2]; const int ok = s_bk[w2];
    if (op > bp || (op == bp && ok < bk)) { bp = op; bk = ok; }
  }
  // near-tie candidate collection: anything within 5e-4 relative of best p
  // (dot-gap 2.5e-4 -- ~25x above worst-case split-bf16 dot error)
  const float thr = bp * (1.0f - 5e-4f);
#pragma unroll
  for (int i = 0; i < 16; ++i) {
    if (v[i][0] >= thr) { const int p = atomicAdd(&s_ccnt, 1); if (p < 16) s_cand[p] = i * 512 + t * 2; }
    if (v[i][1] >= thr) { const int p = atomicAdd(&s_ccnt, 1); if (p < 16) s_cand[p] = i * 512 + t * 2 + 1; }
  }
  __syncthreads();
  if (t == 0) {
    ws_idx[n] = bk;                 // provisional (exact unless near-tie)
    int cc = s_ccnt; if (cc > 16) cc = 16;
    if (cc > 1) {
      const int slot = atomicAdd(rescue_cnt, 1);
      if (slot < MAX_RESCUE) {
        int* e = rescue + slot * ENT_INTS;
        const int cn = cc > 14 ? 14 : cc;
        e[0] = (int)n; e[1] = cn;
        for (int j = 0; j < cn; ++j) e[2 + j] = s_cand[j];
      }
    }
  }
  const float inv = 1.0f / sum;
#pragma unroll
  for (int i = 0; i < 16; ++i) {
    v[i][0] *= inv; v[i][1] *= inv;
    __builtin_nontemporal_store(v[i], (f32x2v*)(row + i * 512 + t * 2));
  }
}

// ---------------- K4b: fp64 rescore of near-tie rows ----------------
__global__ __launch_bounds__(256) void k_rescore(const float* __restrict__ in,
                                                 const float* __restrict__ emb,
                                                 const int* __restrict__ rescue,
                                                 const int* __restrict__ rescue_cnt,
                                                 int* __restrict__ ws_idx) {
  __shared__ double sh[4];
  const int t = threadIdx.x;
  int nent = *rescue_cnt; if (nent > MAX_RESCUE) nent = MAX_RESCUE;
  for (int e = blockIdx.x; e < nent; e += gridDim.x) {
    const int* ent = rescue + e * ENT_INTS;
    const int n = ent[0];
    const int cnt = ent[1];
    const int b = n >> 10, hw = n & 1023;
    const double x = (double)in[(size_t)b * (CDIM * HWSZ) + (size_t)t * HWSZ + hw];
    double sx = x * x;
#pragma unroll
    for (int off = 1; off < 64; off <<= 1) sx += __shfl_xor(sx, off, 64);
    if ((t & 63) == 0) sh[t >> 6] = sx;
    __syncthreads();
    sx = sh[0] + sh[1] + sh[2] + sh[3];
    __syncthreads();
    const double xin = 1.0 / fmax(sqrt(sx), 1e-12);
    double bestS = -2.0; int bestk = 0x7fffffff;
    for (int j = 0; j < cnt; ++j) {
      const int k = ent[2 + j];
      const double w = (double)emb[(size_t)k * CDIM + t];
      double sw = w * w, dp = x * w;
#pragma unroll
      for (int off = 1; off < 64; off <<= 1) { sw += __shfl_xor(sw, off, 64); dp += __shfl_xor(dp, off, 64); }
      if ((t & 63) == 0) sh[t >> 6] = sw;
      __syncthreads();
      sw = sh[0] + sh[1] + sh[2] + sh[3];
      __syncthreads();
      if ((t & 63) == 0) sh[t >> 6] = dp;
      __syncthreads();
      dp = sh[0] + sh[1] + sh[2] + sh[3];
      __syncthreads();
      const double s = dp * xin / fmax(sqrt(sw), 1e-12);  // normalized dot; argmin d == argmax s
      if (s > bestS || (s == bestS && k < bestk)) { bestS = s; bestk = k; }
    }
    if (t == 0) ws_idx[n] = bestk;
  }
}

// ---------------- K4c: final indices output + histogram ----------------
__global__ void k_hist(const int* __restrict__ ws_idx, float* __restrict__ counts,
                       float* __restrict__ out_idx) {
  const int n = blockIdx.x * 256 + threadIdx.x;
  const int k = ws_idx[n];
  out_idx[n] = (float)k;
  atomicAdd(&counts[k], 1.0f);
}

// ---------------- K5: quantized output [B,C,W,H] = emb[idx] gather ----------------
__global__ void k_quant(const float* __restrict__ emb, const int* __restrict__ ws_idx,
                        float* __restrict__ out0) {
  const int b = blockIdx.x >> 8, c = blockIdx.x & 255;
  const int t = threadIdx.x;
  float* dst = out0 + ((size_t)b * CDIM + c) * HWSZ;
#pragma unroll
  for (int p = t; p < HWSZ; p += 256) {
    const int w = p >> 5, h = p & 31;          // p = w*32 + h
    const int n = b * HWSZ + h * 32 + w;
    dst[p] = emb[(size_t)ws_idx[n] * CDIM + c];
  }
}

// ---------------- K6: commitment-loss reduction ----------------
__global__ void k_loss(const float* __restrict__ in, const float* __restrict__ emb,
                       const int* __restrict__ ws_idx, float* __restrict__ loss_acc) {
  const int t = threadIdx.x, lane = t & 63, wv = t >> 6;
  const int b = blockIdx.x >> 4;
  const int hw = ((blockIdx.x & 15) << 6) + lane;
  const int n = b * HWSZ + hw;
  const float* xp = in + (size_t)b * CDIM * HWSZ + hw;
  const float* ep = emb + (size_t)ws_idx[n] * CDIM;
  float ss = 0.f;
#pragma unroll 8
  for (int cc = 0; cc < 64; ++cc) {
    const int c = (wv << 6) + cc;
    const float d = ep[c] - xp[(size_t)c * HWSZ];
    ss = fmaf(d, d, ss);
  }
#pragma unroll
  for (int off = 1; off < 64; off <<= 1) ss += __shfl_xor(ss, off, 64);
  if (lane == 0) atomicAdd(loss_acc, ss);
}

// ---------------- K7: finalize loss + perplexity ----------------
__global__ void k_final(const float* __restrict__ counts, const float* __restrict__ loss_acc,
                        float* __restrict__ out) {
  const int t = threadIdx.x;
  float s = 0.f;
#pragma unroll
  for (int k = t; k < KCB; k += 256) {
    const float avg = counts[k] * (1.0f / (float)NPTS);
    s += avg * logf(avg + 1e-10f);
  }
#pragma unroll
  for (int off = 1; off < 64; off <<= 1) s += __shfl_xor(s, off, 64);
  __shared__ float sw[4];
  if ((t & 63) == 0) sw[t >> 6] = s;
  __syncthreads();
  if (t == 0) {
    const float S = sw[0] + sw[1] + sw[2] + sw[3];
    out[OUT2] = expf(-S);
    out[OUT1] = 0.25f * loss_acc[0] * (1.0f / 4194304.0f);  // /(N*C)
  }
}

extern "C" void kernel_launch(void* const* d_in, const int* in_sizes, int n_in,
                              void* d_out, int out_size, void* d_ws, size_t ws_size,
                              hipStream_t stream) {
  const float* inp = (const float*)d_in[0];
  const float* emb = (const float*)d_in[1];
  float* out = (float*)d_out;
  char* ws = (char*)d_ws;

  bf16* wn_hi     = (bf16*)(ws);                 // 4 MB
  bf16* wn_lo     = (bf16*)(ws + 4194304);       // 4 MB
  float* counts   = (float*)(ws + 8388608);      // 32 KB
  float* loss_a   = (float*)(ws + 8421376);      // 4 B
  int* rescue_cnt = (int*)(ws + 8421380);        // 4 B
  int* ws_idx     = (int*)(ws + 8421632);        // 64 KB
  int* rescue     = (int*)(ws + 8487168);        // 256 KB

  // fn split lives in the (later overwritten) quantized output region: exact 16 MB fit
  bf16* fn_hi = (bf16*)out;
  bf16* fn_lo = ((bf16*)out) + (size_t)NPTS * CDIM;

  (void)hipMemsetAsync(ws + 8388608, 0, 33024, stream);  // counts + loss + rescue_cnt
  k_norm_emb<<<KCB / 4, 256, 0, stream>>>(emb, wn_hi, wn_lo);
  k_norm_x<<<dim3(32, NB), 256, 0, stream>>>(inp, fn_hi, fn_lo);
  k_gemm<<<8192, 256, 0, stream>>>(fn_hi, fn_lo, wn_hi, wn_lo, out + OUT4);
  k_softnorm<<<NPTS, 256, 0, stream>>>(out + OUT4, ws_idx, rescue, rescue_cnt);
  k_rescore<<<256, 256, 0, stream>>>(inp, emb, rescue, rescue_cnt, ws_idx);
  k_hist<<<NPTS / 256, 256, 0, stream>>>(ws_idx, counts, out + OUT3);
  k_quant<<<NB * CDIM, 256, 0, stream>>>(emb, ws_idx, out);
  k_loss<<<256, 256, 0, stream>>>(inp, emb, ws_idx, loss_a);
  k_final<<<1, 256, 0, stream>>>(counts, loss_a, out);
}

// Round 2
// 957.433 us; speedup vs baseline: 1.1273x; 1.0258x over previous
//
#include <hip/hip_runtime.h>

#define NPTS   16384   // B*H*W
#define KCB    8192    // codebook entries
#define CDIM   256
#define HWSZ   1024    // 32*32
#define NB     16      // batch

typedef __bf16 bf16;
typedef __bf16 bf16x4v __attribute__((ext_vector_type(4)));
typedef __bf16 bf16x8v __attribute__((ext_vector_type(8)));
typedef float  f32x4v  __attribute__((ext_vector_type(4)));
typedef float  f32x2v  __attribute__((ext_vector_type(2)));

// flat float offsets in d_out (return order: quantized, loss, perplexity, indices, soft_codes)
#define OUT1 4194304
#define OUT2 4194305
#define OUT3 4194306
#define OUT4 4210690

#define MAX_RESCUE 4096
#define ENT_INTS   16      // [n, cnt, k0..k13]

// ---------------- async 16B global -> LDS ----------------
typedef __attribute__((address_space(1))) unsigned int as1_u32;
typedef __attribute__((address_space(3))) unsigned int as3_u32;
__device__ __forceinline__ void glds16(const bf16* g, bf16* l) {
  __builtin_amdgcn_global_load_lds((as1_u32*)(g), (as3_u32*)(l), 16, 0, 0);
}

// ---------------- K1: fused prep ----------------
// blocks [0,2048): normalize codebook rows (4 rows/block, one wave per row)
// blocks [2048,2560): transpose+normalize inputs (32 hw rows per block)
// block 2560: zero counts/loss_acc/rescue_cnt (8194 dwords)
__global__ void k_prep(const float* __restrict__ emb,
                       bf16* __restrict__ wn_hi, bf16* __restrict__ wn_lo,
                       const float* __restrict__ in,
                       bf16* __restrict__ fn_hi, bf16* __restrict__ fn_lo,
                       float* __restrict__ zero_base) {
  __shared__ float xs[32][257];
  __shared__ float inv_s[32];
  const int t = threadIdx.x;
  const int bid = blockIdx.x;
  if (bid < 2048) {
    const int lane = t & 63;
    const int row  = (bid << 2) + (t >> 6);
    const float4 v = *(const float4*)(emb + (size_t)row * CDIM + (lane << 2));
    float ss = v.x*v.x + v.y*v.y + v.z*v.z + v.w*v.w;
#pragma unroll
    for (int off = 1; off < 64; off <<= 1) ss += __shfl_xor(ss, off, 64);
    const float inv = 1.0f / fmaxf(sqrtf(ss), 1e-12f);
    const float a0 = v.x*inv, a1 = v.y*inv, a2 = v.z*inv, a3 = v.w*inv;
    const bf16 h0 = (bf16)a0, h1 = (bf16)a1, h2 = (bf16)a2, h3 = (bf16)a3;
    const bf16 l0 = (bf16)(a0 - (float)h0), l1 = (bf16)(a1 - (float)h1),
               l2 = (bf16)(a2 - (float)h2), l3 = (bf16)(a3 - (float)h3);
    *(bf16x4v*)(wn_hi + (size_t)row * CDIM + (lane << 2)) = (bf16x4v){h0, h1, h2, h3};
    *(bf16x4v*)(wn_lo + (size_t)row * CDIM + (lane << 2)) = (bf16x4v){l0, l1, l2, l3};
    return;
  }
  if (bid == 2560) {
    for (int i = t; i < 8194; i += 256) zero_base[i] = 0.0f;
    return;
  }
  const int bx = bid - 2048;
  const int b = bx >> 5;               // 16
  const int hw0 = (bx & 31) << 5;      // 32 hw rows per block
  const int hwo = t & 31, cb = t >> 5; // cb in [0,8)
  const float* src = in + (size_t)b * CDIM * HWSZ + hw0 + hwo;
#pragma unroll
  for (int it = 0; it < 32; ++it) {
    const int c = cb + (it << 3);
    xs[hwo][c] = src[(size_t)c * HWSZ];   // coalesced along hw
  }
  __syncthreads();
  const int wv = t >> 6, lane = t & 63;
#pragma unroll
  for (int j = 0; j < 8; ++j) {
    const int r = wv + (j << 2);
    float ss = 0.f;
#pragma unroll
    for (int e = 0; e < 4; ++e) { const float x = xs[r][lane + (e << 6)]; ss = fmaf(x, x, ss); }
#pragma unroll
    for (int off = 1; off < 64; off <<= 1) ss += __shfl_xor(ss, off, 64);
    if (lane == 0) inv_s[r] = 1.0f / fmaxf(sqrtf(ss), 1e-12f);
  }
  __syncthreads();
#pragma unroll 4
  for (int r = 0; r < 32; ++r) {
    const float v = xs[r][t] * inv_s[r];
    const bf16 h = (bf16)v;
    const bf16 l = (bf16)(v - (float)h);
    const size_t n = (size_t)b * HWSZ + hw0 + r;
    fn_hi[n * CDIM + t] = h;   // coalesced along c
    fn_lo[n * CDIM + t] = l;
  }
}

// ---------------- K3: split-bf16 MFMA GEMM -> unnormalized exp(-distance) ----------------
// Grid: 8192 1-D blocks. XCD-aware supertile swizzle (bid&7 == xcd round-robin).
__global__ __launch_bounds__(256) void k_gemm(
    const bf16* __restrict__ fn_hi, const bf16* __restrict__ fn_lo,
    const bf16* __restrict__ wn_hi, const bf16* __restrict__ wn_lo,
    float* __restrict__ soft) {
  __shared__ __align__(16) bf16 Ah[128 * 32];
  __shared__ __align__(16) bf16 Al[128 * 32];
  __shared__ __align__(16) bf16 Bh[128 * 32];
  __shared__ __align__(16) bf16 Bl[128 * 32];
  const int t = threadIdx.x;

  const int bid = blockIdx.x;
  const int xcd = bid & 7;
  const int g   = bid >> 3;             // 0..1023 per XCD
  const int s   = (xcd << 3) + (g >> 7);  // supertile 0..63 ; s>>3 == xcd
  const int w   = g & 127;
  const int rowt = ((s >> 3) << 4) + (w >> 3);   // 0..127
  const int colt = ((s & 7) << 3) + (w & 7);     // 0..63
  const int row0 = rowt << 7;   // data points
  const int col0 = colt << 7;   // codebook

  const int r0 = t >> 2;
  const int cs = (t & 3) << 3;
  const int wv = t >> 6, lane = t & 63;
  const int wm = (wv & 1) << 6, wnn = (wv >> 1) << 6;
  const int ml = lane & 15, quad = lane >> 4;

  const size_t gA0 = (size_t)(row0 + r0) * CDIM + cs;
  const size_t gA1 = gA0 + (size_t)64 * CDIM;
  const size_t gB0 = (size_t)(col0 + r0) * CDIM + cs;
  const size_t gB1 = gB0 + (size_t)64 * CDIM;

  f32x4v acc[4][4] = {};

  for (int c0 = 0; c0 < CDIM; c0 += 32) {
    __syncthreads();
    glds16(fn_hi + gA0 + c0, Ah + t * 8);
    glds16(fn_hi + gA1 + c0, Ah + (t + 256) * 8);
    glds16(fn_lo + gA0 + c0, Al + t * 8);
    glds16(fn_lo + gA1 + c0, Al + (t + 256) * 8);
    glds16(wn_hi + gB0 + c0, Bh + t * 8);
    glds16(wn_hi + gB1 + c0, Bh + (t + 256) * 8);
    glds16(wn_lo + gB0 + c0, Bl + t * 8);
    glds16(wn_lo + gB1 + c0, Bl + (t + 256) * 8);
    __syncthreads();
    bf16x8v ah[4], alo[4], bh[4], blo[4];
#pragma unroll
    for (int i = 0; i < 4; ++i) {
      const int ra = (wm + 16 * i + ml) * 32 + quad * 8;
      const int rb = (wnn + 16 * i + ml) * 32 + quad * 8;
      ah[i]  = *(const bf16x8v*)(Ah + ra);
      alo[i] = *(const bf16x8v*)(Al + ra);
      bh[i]  = *(const bf16x8v*)(Bh + rb);
      blo[i] = *(const bf16x8v*)(Bl + rb);
    }
#pragma unroll
    for (int i = 0; i < 4; ++i)
#pragma unroll
      for (int j = 0; j < 4; ++j) {
        acc[i][j] = __builtin_amdgcn_mfma_f32_16x16x32_bf16(alo[i], bh[j], acc[i][j], 0, 0, 0);
        acc[i][j] = __builtin_amdgcn_mfma_f32_16x16x32_bf16(ah[i], blo[j], acc[i][j], 0, 0, 0);
        acc[i][j] = __builtin_amdgcn_mfma_f32_16x16x32_bf16(ah[i], bh[j], acc[i][j], 0, 0, 0);
      }
  }
  // epilogue: p_un = exp(2*dot - 2) ; C/D layout: col=lane&15, row=quad*4+reg
#pragma unroll
  for (int i = 0; i < 4; ++i) {
#pragma unroll
    for (int r = 0; r < 4; ++r) {
      const size_t nrow = (size_t)row0 + wm + 16 * i + quad * 4 + r;
      float* dst = soft + nrow * KCB + col0 + wnn + ml;
#pragma unroll
      for (int j = 0; j < 4; ++j)
        __builtin_nontemporal_store(__expf(fmaf(2.0f, acc[i][j][r], -2.0f)), dst + 16 * j);
    }
  }
}

// ---------------- K4: per-row softmax normalize (in place) + approx argmax + near-tie rescue ----------------
__global__ __launch_bounds__(256) void k_softnorm(float* __restrict__ soft,
                                                  int* __restrict__ ws_idx,
                                                  int* __restrict__ rescue,
                                                  int* __restrict__ rescue_cnt) {
  const int t = threadIdx.x;
  const size_t n = blockIdx.x;
  float* row = soft + n * (size_t)KCB;
  f32x2v v[16];
  float sum = 0.f, bp = -1.f;
  int bk = 0;
#pragma unroll
  for (int i = 0; i < 16; ++i) {
    v[i] = __builtin_nontemporal_load((const f32x2v*)(row + i * 512 + t * 2));
    const int k0 = i * 512 + t * 2;
    if (v[i][0] > bp) { bp = v[i][0]; bk = k0; }
    if (v[i][1] > bp) { bp = v[i][1]; bk = k0 + 1; }
    sum += v[i][0] + v[i][1];
  }
#pragma unroll
  for (int off = 1; off < 64; off <<= 1) {
    sum += __shfl_xor(sum, off, 64);
    const float op = __shfl_xor(bp, off, 64);
    const int   ok = __shfl_xor(bk, off, 64);
    if (op > bp || (op == bp && ok < bk)) { bp = op; bk = ok; }
  }
  __shared__ float s_sum[4], s_bp[4];
  __shared__ int s_bk[4];
  __shared__ int s_cand[16];
  __shared__ int s_ccnt;
  const int wv = t >> 6;
  if (t == 0) s_ccnt = 0;
  if ((t & 63) == 0) { s_sum[wv] = sum; s_bp[wv] = bp; s_bk[wv] = bk; }
  __syncthreads();
  sum = s_sum[0] + s_sum[1] + s_sum[2] + s_sum[3];
  bp = s_bp[0]; bk = s_bk[0];
#pragma unroll
  for (int w2 = 1; w2 < 4; ++w2) {
    const float op = s_bp[w2]; const int ok = s_bk[w2];
    if (op > bp || (op == bp && ok < bk)) { bp = op; bk = ok; }
  }
  // near-tie candidate collection: anything within 5e-4 relative of best p
  const float thr = bp * (1.0f - 5e-4f);
#pragma unroll
  for (int i = 0; i < 16; ++i) {
    if (v[i][0] >= thr) { const int p = atomicAdd(&s_ccnt, 1); if (p < 16) s_cand[p] = i * 512 + t * 2; }
    if (v[i][1] >= thr) { const int p = atomicAdd(&s_ccnt, 1); if (p < 16) s_cand[p] = i * 512 + t * 2 + 1; }
  }
  __syncthreads();
  if (t == 0) {
    ws_idx[n] = bk;                 // provisional (exact unless near-tie)
    int cc = s_ccnt; if (cc > 16) cc = 16;
    if (cc > 1) {
      const int slot = atomicAdd(rescue_cnt, 1);
      if (slot < MAX_RESCUE) {
        int* e = rescue + slot * ENT_INTS;
        const int cn = cc > 14 ? 14 : cc;
        e[0] = (int)n; e[1] = cn;
        for (int j = 0; j < cn; ++j) e[2 + j] = s_cand[j];
      }
    }
  }
  const float inv = 1.0f / sum;
#pragma unroll
  for (int i = 0; i < 16; ++i) {
    v[i][0] *= inv; v[i][1] *= inv;
    __builtin_nontemporal_store(v[i], (f32x2v*)(row + i * 512 + t * 2));
  }
}

// ---------------- K4b: fp64 rescore of near-tie rows ----------------
__global__ __launch_bounds__(256) void k_rescore(const float* __restrict__ in,
                                                 const float* __restrict__ emb,
                                                 const int* __restrict__ rescue,
                                                 const int* __restrict__ rescue_cnt,
                                                 int* __restrict__ ws_idx) {
  __shared__ double sh[4];
  const int t = threadIdx.x;
  int nent = *rescue_cnt; if (nent > MAX_RESCUE) nent = MAX_RESCUE;
  for (int e = blockIdx.x; e < nent; e += gridDim.x) {
    const int* ent = rescue + e * ENT_INTS;
    const int n = ent[0];
    const int cnt = ent[1];
    const int b = n >> 10, hw = n & 1023;
    const double x = (double)in[(size_t)b * (CDIM * HWSZ) + (size_t)t * HWSZ + hw];
    double sx = x * x;
#pragma unroll
    for (int off = 1; off < 64; off <<= 1) sx += __shfl_xor(sx, off, 64);
    if ((t & 63) == 0) sh[t >> 6] = sx;
    __syncthreads();
    sx = sh[0] + sh[1] + sh[2] + sh[3];
    __syncthreads();
    const double xin = 1.0 / fmax(sqrt(sx), 1e-12);
    double bestS = -2.0; int bestk = 0x7fffffff;
    for (int j = 0; j < cnt; ++j) {
      const int k = ent[2 + j];
      const double w = (double)emb[(size_t)k * CDIM + t];
      double sw = w * w, dp = x * w;
#pragma unroll
      for (int off = 1; off < 64; off <<= 1) { sw += __shfl_xor(sw, off, 64); dp += __shfl_xor(dp, off, 64); }
      if ((t & 63) == 0) sh[t >> 6] = sw;
      __syncthreads();
      sw = sh[0] + sh[1] + sh[2] + sh[3];
      __syncthreads();
      if ((t & 63) == 0) sh[t >> 6] = dp;
      __syncthreads();
      dp = sh[0] + sh[1] + sh[2] + sh[3];
      __syncthreads();
      const double s = dp * xin / fmax(sqrt(sw), 1e-12);  // normalized dot; argmin d == argmax s
      if (s > bestS || (s == bestS && k < bestk)) { bestS = s; bestk = k; }
    }
    if (t == 0) ws_idx[n] = bestk;
  }
}

// ---------------- K5: fused post pass ----------------
// blocks [0,512): quantized output via LDS-transposed gather.
//   block = (b = bid>>5, cg = bid&31); c0 = cg*8. Phase 1: for each of the 1024
//   points of batch b, read emb[idx][c0..c0+7] as 2 float4 (32B contiguous) into
//   a swizzled LDS tile. Phase 2: fully-coalesced nt writes of out[b][c][.].
// blocks [512,768): commitment loss partial sums.
// blocks [768,832): histogram + index output.
__global__ __launch_bounds__(256) void k_postq(const float* __restrict__ emb,
                                               const int* __restrict__ ws_idx,
                                               float* __restrict__ out0,
                                               const float* __restrict__ in,
                                               float* __restrict__ loss_acc,
                                               float* __restrict__ counts,
                                               float* __restrict__ out_idx) {
  __shared__ float q[1024 * 9];   // pitch 9 + rotate-by-(n>>5) swizzle: <=4-way on read
  const int t = threadIdx.x;
  const int bid = blockIdx.x;
  if (bid < 512) {
    const int b = bid >> 5, cg = bid & 31;
    const int c0 = cg << 3;
    const int* wsi = ws_idx + b * HWSZ;
#pragma unroll
    for (int it = 0; it < 8; ++it) {
      const int task = t + (it << 8);      // 2048 tasks: (n, half)
      const int n = task >> 1, part = task & 1;
      const int k = wsi[n];
      const float4 v = *(const float4*)(emb + (size_t)k * CDIM + c0 + (part << 2));
      const int s = n >> 5;
      float* row = q + n * 9;
      row[((part << 2) + 0 + s) & 7] = v.x;
      row[((part << 2) + 1 + s) & 7] = v.y;
      row[((part << 2) + 2 + s) & 7] = v.z;
      row[((part << 2) + 3 + s) & 7] = v.w;
    }
    __syncthreads();
#pragma unroll
    for (int co = 0; co < 8; ++co) {
      const int c = c0 + co;
      float* dst = out0 + ((size_t)b * CDIM + c) * HWSZ;
#pragma unroll
      for (int p = t; p < HWSZ; p += 256) {
        const int n = ((p & 31) << 5) | (p >> 5);   // n = h*32 + w, p = w*32 + h
        __builtin_nontemporal_store(q[n * 9 + ((co + (n >> 5)) & 7)], dst + p);
      }
    }
    return;
  }
  if (bid < 768) {
    const int bb = bid - 512;
    const int lane = t & 63, wv = t >> 6;
    const int b = bb >> 4;
    const int hw = ((bb & 15) << 6) + lane;
    const int n = b * HWSZ + hw;
    const float* xp = in + (size_t)b * CDIM * HWSZ + hw;
    const float* ep = emb + (size_t)ws_idx[n] * CDIM;
    float ss = 0.f;
#pragma unroll 8
    for (int cc = 0; cc < 64; ++cc) {
      const int c = (wv << 6) + cc;
      const float d = ep[c] - xp[(size_t)c * HWSZ];
      ss = fmaf(d, d, ss);
    }
#pragma unroll
    for (int off = 1; off < 64; off <<= 1) ss += __shfl_xor(ss, off, 64);
    if (lane == 0) atomicAdd(loss_acc, ss);
    return;
  }
  const int n = (bid - 768) * 256 + t;
  const int k = ws_idx[n];
  out_idx[n] = (float)k;
  atomicAdd(&counts[k], 1.0f);
}

// ---------------- K7: finalize loss + perplexity ----------------
__global__ void k_final(const float* __restrict__ counts, const float* __restrict__ loss_acc,
                        float* __restrict__ out) {
  const int t = threadIdx.x;
  float s = 0.f;
#pragma unroll
  for (int k = t; k < KCB; k += 256) {
    const float avg = counts[k] * (1.0f / (float)NPTS);
    s += avg * logf(avg + 1e-10f);
  }
#pragma unroll
  for (int off = 1; off < 64; off <<= 1) s += __shfl_xor(s, off, 64);
  __shared__ float sw[4];
  if ((t & 63) == 0) sw[t >> 6] = s;
  __syncthreads();
  if (t == 0) {
    const float S = sw[0] + sw[1] + sw[2] + sw[3];
    out[OUT2] = expf(-S);
    out[OUT1] = 0.25f * loss_acc[0] * (1.0f / 4194304.0f);  // /(N*C)
  }
}

extern "C" void kernel_launch(void* const* d_in, const int* in_sizes, int n_in,
                              void* d_out, int out_size, void* d_ws, size_t ws_size,
                              hipStream_t stream) {
  const float* inp = (const float*)d_in[0];
  const float* emb = (const float*)d_in[1];
  float* out = (float*)d_out;
  char* ws = (char*)d_ws;

  bf16* wn_hi     = (bf16*)(ws);                 // 4 MB
  bf16* wn_lo     = (bf16*)(ws + 4194304);       // 4 MB
  float* counts   = (float*)(ws + 8388608);      // 32 KB
  float* loss_a   = (float*)(ws + 8421376);      // 4 B   (= counts + 8192)
  int* rescue_cnt = (int*)(ws + 8421380);        // 4 B   (= counts + 8193)
  int* ws_idx     = (int*)(ws + 8421632);        // 64 KB
  int* rescue     = (int*)(ws + 8487168);        // 256 KB

  // fn split lives in the (later overwritten) quantized output region: exact 16 MB fit
  bf16* fn_hi = (bf16*)out;
  bf16* fn_lo = ((bf16*)out) + (size_t)NPTS * CDIM;

  k_prep<<<2561, 256, 0, stream>>>(emb, wn_hi, wn_lo, inp, fn_hi, fn_lo, counts);
  k_gemm<<<8192, 256, 0, stream>>>(fn_hi, fn_lo, wn_hi, wn_lo, out + OUT4);
  k_softnorm<<<NPTS, 256, 0, stream>>>(out + OUT4, ws_idx, rescue, rescue_cnt);
  k_rescore<<<256, 256, 0, stream>>>(inp, emb, rescue, rescue_cnt, ws_idx);
  k_postq<<<832, 256, 0, stream>>>(emb, ws_idx, out, inp, loss_a, counts, out + OUT3);
  k_final<<<1, 256, 0, stream>>>(counts, loss_a, out);
}